// Round 1
// baseline (19125.044 us; speedup 1.0000x reference)
//
#include <hip/hip_runtime.h>
#include <hip/hip_fp16.h>

#define Hh 2048
#define VV 256
#define SS 2048
#define TT 2048
#define NB 256
#define NT 512

typedef _Float16 h4 __attribute__((ext_vector_type(4)));
typedef _Float16 h2 __attribute__((ext_vector_type(2)));
typedef unsigned int u32x4 __attribute__((ext_vector_type(4)));
typedef unsigned short u16x4 __attribute__((ext_vector_type(4)));

#if defined(__has_builtin)
#if __has_builtin(__builtin_amdgcn_fdot2)
#define FDOT2(a, b, c) __builtin_amdgcn_fdot2((a), (b), (c), false)
#endif
#endif
#ifndef FDOT2
#define FDOT2(a, b, c) \
  fmaf((float)(a).x, (float)(b).x, fmaf((float)(a).y, (float)(b).y, (c)))
#endif

// ---------------------------------------------------------------------------
// Generic NT GEMM: C[M][N] = A[M,K] . B[N,K]^T (+ biasM[m]) (+ biasN[n])
// ---------------------------------------------------------------------------
__global__ __launch_bounds__(256) void gemm_nt(const float* __restrict__ A,
                                               const float* __restrict__ B,
                                               const float* __restrict__ biasM,
                                               const float* __restrict__ biasN,
                                               float* __restrict__ C,
                                               int M, int N, int K) {
  __shared__ __align__(16) float At[32][68];
  __shared__ __align__(16) float Bt[32][68];
  const int t = threadIdx.x;
  const int m0 = blockIdx.x << 6, n0 = blockIdx.y << 6;
  const int r0 = t >> 3, c4 = (t & 7) << 2;
  const int tm = (t >> 4) << 2, tn = (t & 15) << 2;
  float acc[4][4];
#pragma unroll
  for (int i = 0; i < 4; ++i)
#pragma unroll
    for (int j = 0; j < 4; ++j) acc[i][j] = 0.f;

  for (int k0 = 0; k0 < K; k0 += 32) {
    float4 a0 = *(const float4*)&A[(size_t)(m0 + r0) * K + k0 + c4];
    float4 a1 = *(const float4*)&A[(size_t)(m0 + r0 + 32) * K + k0 + c4];
    float4 b0 = *(const float4*)&B[(size_t)(n0 + r0) * K + k0 + c4];
    float4 b1 = *(const float4*)&B[(size_t)(n0 + r0 + 32) * K + k0 + c4];
    __syncthreads();
    At[c4 + 0][r0] = a0.x; At[c4 + 1][r0] = a0.y; At[c4 + 2][r0] = a0.z; At[c4 + 3][r0] = a0.w;
    At[c4 + 0][r0 + 32] = a1.x; At[c4 + 1][r0 + 32] = a1.y; At[c4 + 2][r0 + 32] = a1.z; At[c4 + 3][r0 + 32] = a1.w;
    Bt[c4 + 0][r0] = b0.x; Bt[c4 + 1][r0] = b0.y; Bt[c4 + 2][r0] = b0.z; Bt[c4 + 3][r0] = b0.w;
    Bt[c4 + 0][r0 + 32] = b1.x; Bt[c4 + 1][r0 + 32] = b1.y; Bt[c4 + 2][r0 + 32] = b1.z; Bt[c4 + 3][r0 + 32] = b1.w;
    __syncthreads();
#pragma unroll
    for (int k = 0; k < 32; ++k) {
      float4 av = *(const float4*)&At[k][tm];
      float4 bv = *(const float4*)&Bt[k][tn];
      acc[0][0] = fmaf(av.x, bv.x, acc[0][0]);
      acc[0][1] = fmaf(av.x, bv.y, acc[0][1]);
      acc[0][2] = fmaf(av.x, bv.z, acc[0][2]);
      acc[0][3] = fmaf(av.x, bv.w, acc[0][3]);
      acc[1][0] = fmaf(av.y, bv.x, acc[1][0]);
      acc[1][1] = fmaf(av.y, bv.y, acc[1][1]);
      acc[1][2] = fmaf(av.y, bv.z, acc[1][2]);
      acc[1][3] = fmaf(av.y, bv.w, acc[1][3]);
      acc[2][0] = fmaf(av.z, bv.x, acc[2][0]);
      acc[2][1] = fmaf(av.z, bv.y, acc[2][1]);
      acc[2][2] = fmaf(av.z, bv.z, acc[2][2]);
      acc[2][3] = fmaf(av.z, bv.w, acc[2][3]);
      acc[3][0] = fmaf(av.w, bv.x, acc[3][0]);
      acc[3][1] = fmaf(av.w, bv.y, acc[3][1]);
      acc[3][2] = fmaf(av.w, bv.z, acc[3][2]);
      acc[3][3] = fmaf(av.w, bv.w, acc[3][3]);
    }
  }
#pragma unroll
  for (int i = 0; i < 4; ++i) {
    float bm = biasM ? biasM[m0 + tm + i] : 0.f;
#pragma unroll
    for (int j = 0; j < 4; ++j) {
      float bn = biasN ? biasN[n0 + tn + j] : 0.f;
      C[(size_t)(m0 + tm + i) * N + n0 + tn + j] = acc[i][j] + bm + bn;
    }
  }
}

// ---------------------------------------------------------------------------
// Persistent recurrence kernel — barrier-free tagged dataflow.
//
// h exchange: hb is uint32[2][2048]; slot = (16-bit epoch tag << 16 | fp16 h
// bits), written/read with agent-scope (MALL-coherent, L2-bypassing) ops.
// Reader of step s polls buffer s&1 for tag s+1 (one global_load_dwordx4
// sc0 sc1 covers its 4 slots). Producer at step s writes tag s+2 into buffer
// (s+1)&1. Init: owner block writes (fp16 0.0, tag 1). Tags are +1-offset so
// zero/stale memory can't alias. Buffer-reuse safety: a producer writes epoch
// e+2 only after polling ALL slots of e+1, and any block's e+1 write happens
// after ALL its threads read epoch e (stage -> __syncthreads -> lane0 write).
//
// The consumer only ever uses h as fp16 (it was already converting fp32->fp16
// into LDS), so broadcasting producer-converted fp16 is numerically identical.
//
// Recurrent weights live in VGPRs: each wave holds its 3 gate rows as 24 x h4
// (48 VGPRs/lane) — no per-step LDS weight stream, and the enc->dec swap at
// step SS is a private register reload (no shared-state hazard, no barrier).
// h16 is double-buffered by step parity so the trailing barrier is dropped.
// ---------------------------------------------------------------------------
__global__ __launch_bounds__(NT) void recur_kernel(
    const float* __restrict__ giT_enc, const float* __restrict__ giT_dec,
    const float* __restrict__ enc_w_hh, const float* __restrict__ enc_b_hh,
    const float* __restrict__ dec_w_hh, const float* __restrict__ dec_b_hh,
    const int* __restrict__ inputs, const int* __restrict__ targets,
    unsigned int* __restrict__ hb, float* __restrict__ dec_hs) {
  __shared__ __align__(16) float gi_lds[24 * VV];       // 24 KB
  __shared__ __align__(16) _Float16 h16[2][Hh];         // 8 KB (double buffer)
  __shared__ __align__(16) unsigned short tok_lds[SS];  // 4 KB
  __shared__ float gidec_lds[48];

  const int t = threadIdx.x;
  const int b = blockIdx.x;
  const int bks = b << 3;
  const int w = t >> 6, l = t & 63;

  // ---- recurrent weights + biases for this wave's h row, in registers
  h4 wreg[24];
  float br_, bz_, bn_;
  auto load_wb = [&](const float* W, const float* B) {
#pragma unroll
    for (int g = 0; g < 3; ++g) {
      const float* rb = W + ((size_t)(g * Hh + bks + w)) * Hh + (l << 2);
#pragma unroll
      for (int q = 0; q < 8; ++q) {
        float4 vv = *(const float4*)&rb[q * 256];
        wreg[g * 8 + q] = h4{(_Float16)vv.x, (_Float16)vv.y,
                            (_Float16)vv.z, (_Float16)vv.w};
      }
    }
    br_ = B[bks + w];
    bz_ = B[Hh + bks + w];
    bn_ = B[2 * Hh + bks + w];
  };
  load_wb(enc_w_hh, enc_b_hh);

  // ---- stage encoder per-vocab input-gate slice: gi_lds[(g*8+j)*256 + v]
  for (int r = 0; r < 24; ++r) {
    const int g = r >> 3, j = r & 7;
    const float4* src = (const float4*)(giT_enc + ((size_t)(g * Hh + bks + j)) * VV);
    if (t < 64) ((float4*)&gi_lds[r * VV])[t] = src[t];
  }

  // ---- tokens
  for (int u = t; u < SS; u += NT) tok_lds[u] = (unsigned short)inputs[u];

  // ---- decoder input-gates: only tokens {0, targets[1]}
  if (t < 48) {
    const int sel = t / 24, r = t % 24;
    const int tk = sel ? targets[1] : 0;
    const int g = r >> 3, jj = r & 7;
    gidec_lds[sel * 24 + r] = giT_dec[((size_t)(g * Hh + bks + jj)) * VV + tk];
  }

  // ---- init own h slots: fp16 0.0 (bits 0), tag 1 (buffer 0)
  if (t < 8) {
    __hip_atomic_store(&hb[bks + t], 0x00010000u, __ATOMIC_RELAXED,
                       __HIP_MEMORY_SCOPE_AGENT);
  }
  float hprev = 0.0f;  // lane 0 of wave w: running fp32 h[bks+w]

  for (int step = 0; step < SS + TT; ++step) {
    if (step == SS) load_wb(dec_w_hh, dec_b_hh);  // private regs: no hazard
    const int sb = step & 1;

    // ---- poll the 4 tagged 32-bit slots this thread stages (one dwordx4)
    {
      const unsigned int* addr = hb + ((size_t)sb << 11) + (t << 2);
      const unsigned int want = ((unsigned int)(step + 1)) << 16;
      u32x4 v;
      for (;;) {
        asm volatile(
            "global_load_dwordx4 %0, %1, off sc0 sc1\n\t"
            "s_waitcnt vmcnt(0)"
            : "=&v"(v)
            : "v"(addr)
            : "memory");
        if ((v.x & 0xFFFF0000u) == want && (v.y & 0xFFFF0000u) == want &&
            (v.z & 0xFFFF0000u) == want && (v.w & 0xFFFF0000u) == want)
          break;
        __builtin_amdgcn_s_sleep(1);
      }
      u16x4 hu = {(unsigned short)v.x, (unsigned short)v.y,
                  (unsigned short)v.z, (unsigned short)v.w};
      *(u16x4*)&h16[sb][t << 2] = hu;
    }
    __syncthreads();

    // ---- three gate-row dot products for h index bks+w (fp16 dot2, fp32 acc)
    float ar = 0.f, az = 0.f, an = 0.f;
#pragma unroll
    for (int q = 0; q < 8; ++q) {
      const int c = q * 256 + (l << 2);
      h4 hv = *(const h4*)&h16[sb][c];
      h2 hlo = __builtin_shufflevector(hv, hv, 0, 1);
      h2 hhi = __builtin_shufflevector(hv, hv, 2, 3);
      h4 wr4 = wreg[q];
      h4 wz4 = wreg[8 + q];
      h4 wn4 = wreg[16 + q];
      ar = FDOT2(__builtin_shufflevector(wr4, wr4, 0, 1), hlo, ar);
      ar = FDOT2(__builtin_shufflevector(wr4, wr4, 2, 3), hhi, ar);
      az = FDOT2(__builtin_shufflevector(wz4, wz4, 0, 1), hlo, az);
      az = FDOT2(__builtin_shufflevector(wz4, wz4, 2, 3), hhi, az);
      an = FDOT2(__builtin_shufflevector(wn4, wn4, 0, 1), hlo, an);
      an = FDOT2(__builtin_shufflevector(wn4, wn4, 2, 3), hhi, an);
    }
#pragma unroll
    for (int off = 32; off > 0; off >>= 1) {
      ar += __shfl_xor(ar, off);
      az += __shfl_xor(az, off);
      an += __shfl_xor(an, off);
    }

    if (l == 0) {
      float gr, gz, gn;
      if (step < SS) {
        const int tk = tok_lds[step];
        gr = gi_lds[(0 + w) * VV + tk];
        gz = gi_lds[(8 + w) * VV + tk];
        gn = gi_lds[(16 + w) * VV + tk];
      } else {
        const int sel = (step == SS) ? 0 : 24;
        gr = gidec_lds[sel + w];
        gz = gidec_lds[sel + 8 + w];
        gn = gidec_lds[sel + 16 + w];
      }
      const float xr = gr + ar + br_;
      const float xz = gz + az + bz_;
      const float hn = an + bn_;
      const float rr = 1.f / (1.f + __expf(-xr));
      const float zz = 1.f / (1.f + __expf(-xz));
      const float nn = tanhf(gn + rr * hn);
      const float hnew = (1.f - zz) * nn + zz * hprev;

      _Float16 hf = (_Float16)hnew;
      const unsigned int pk =
          (((unsigned int)(step + 2)) << 16) |
          (unsigned int)__builtin_bit_cast(unsigned short, hf);
      __hip_atomic_store(&hb[(((size_t)((step + 1) & 1)) << 11) + bks + w], pk,
                         __ATOMIC_RELAXED, __HIP_MEMORY_SCOPE_AGENT);
      if (step >= SS) dec_hs[(size_t)(step - SS) * Hh + bks + w] = hnew;
      hprev = hnew;
    }
    // no trailing barrier: h16 is double-buffered; weights/biases are private
  }
}

// ---------------------------------------------------------------------------
extern "C" void kernel_launch(void* const* d_in, const int* in_sizes, int n_in,
                              void* d_out, int out_size, void* d_ws, size_t ws_size,
                              hipStream_t stream) {
  (void)in_sizes; (void)n_in; (void)out_size; (void)ws_size;
  const int* inputs = (const int*)d_in[0];
  const int* targets = (const int*)d_in[1];
  const float* emb = (const float*)d_in[2];
  const float* enc_w_ih = (const float*)d_in[3];
  const float* enc_w_hh = (const float*)d_in[4];
  const float* enc_b_ih = (const float*)d_in[5];
  const float* enc_b_hh = (const float*)d_in[6];
  const float* dec_w_ih = (const float*)d_in[7];
  const float* dec_w_hh = (const float*)d_in[8];
  const float* dec_b_ih = (const float*)d_in[9];
  const float* dec_b_hh = (const float*)d_in[10];
  const float* fc_w = (const float*)d_in[11];
  const float* fc_b = (const float*)d_in[12];
  float* out = (float*)d_out;

  // workspace layout
  float* giT_enc = (float*)d_ws;                          // [6144][256]
  float* giT_dec = giT_enc + (size_t)6144 * 256;          // [6144][256]
  float* dec_hs = giT_dec + (size_t)6144 * 256;           // [2048][2048]
  unsigned int* hb =
      (unsigned int*)(dec_hs + (size_t)TT * Hh);          // [2][2048] tagged u32

  // per-vocab input-gate tables: giT[r][v] = W_ih[r] . emb[v] + b_ih[r]
  gemm_nt<<<dim3(96, 4), 256, 0, stream>>>(enc_w_ih, emb, enc_b_ih, nullptr,
                                           giT_enc, 3 * Hh, VV, Hh);
  gemm_nt<<<dim3(96, 4), 256, 0, stream>>>(dec_w_ih, emb, dec_b_ih, nullptr,
                                           giT_dec, 3 * Hh, VV, Hh);

  void* args[] = {&giT_enc, &giT_dec, &enc_w_hh, &enc_b_hh, &dec_w_hh,
                  &dec_b_hh, &inputs, &targets, &hb, &dec_hs};
  hipError_t e = hipLaunchCooperativeKernel((void*)recur_kernel, dim3(NB),
                                            dim3(NT), args, 0, stream);
  if (e != hipSuccess) {
    recur_kernel<<<dim3(NB), dim3(NT), 0, stream>>>(
        giT_enc, giT_dec, enc_w_hh, enc_b_hh, dec_w_hh, dec_b_hh, inputs,
        targets, hb, dec_hs);
  }

  // out[t][v] = dec_hs[t] . fc_w[v] + fc_b[v]
  gemm_nt<<<dim3(32, 4), 256, 0, stream>>>(dec_hs, fc_w, nullptr, fc_b, out,
                                           TT, VV, Hh);
}